// Round 4
// baseline (1574.331 us; speedup 1.0000x reference)
//
#include <hip/hip_runtime.h>
#include <hip/hip_bf16.h>

// VisualDecoder: B=8,N=4096,D=768,H=12,M=64,L=4,HD=64.
// Inputs/outputs are FLOAT32 (per reference setup_inputs). Compute in bf16
// MFMA (f32 accum): inputs converted once to bf16 in ws (flat convert for
// tokens/selector; fused f32->bf16 transpose for weights/tokens^T).
// All GEMMs: C = A · B^T, both operands contiguous in K, fp32 accum via
// v_mfma_f32_16x16x32_bf16. Biases/gains read as f32 directly in epilogues.

using bf16 = __hip_bfloat16;
typedef __attribute__((ext_vector_type(8))) __bf16 bf16x8;
typedef __attribute__((ext_vector_type(4))) float f32x4;
typedef unsigned int u32;
typedef __attribute__((ext_vector_type(4))) u32 u32x4;

#define DEVINL __device__ __forceinline__

DEVINL float bf2f(bf16 v) { return __bfloat162float(v); }
DEVINL bf16 f2bf(float v) { return __float2bfloat16(v); }
DEVINL u32 f2bfu(float f) { bf16 h = __float2bfloat16(f); return *(unsigned short*)&h; }
DEVINL float gelu_f(float x) { return 0.5f * x * (1.0f + erff(x * 0.70710678118654752f)); }

// ---------------------------------------------------------------- flat f32 -> bf16
__global__ __launch_bounds__(256) void cvt_f2b(const float* in, bf16* out, long n) {
  const long i = ((long)blockIdx.x * 256 + threadIdx.x) * 8;
  if (i >= n) return;
  float4 a = *(const float4*)(in + i);
  float4 b = *(const float4*)(in + i + 4);
  u32 w[4];
  w[0] = f2bfu(a.x) | (f2bfu(a.y) << 16);
  w[1] = f2bfu(a.z) | (f2bfu(a.w) << 16);
  w[2] = f2bfu(b.x) | (f2bfu(b.y) << 16);
  w[3] = f2bfu(b.z) | (f2bfu(b.w) << 16);
  *(u32x4*)(out + i) = *(u32x4*)w;
}

// ---------------------------------------------------------------- big GEMM
// 128x128 tile, BK=32, 256 thr = 4 waves (2x2 of 64x64), M%128==N%128==K%32==0.
struct GemmBigP {
  const bf16* A; const bf16* B; bf16* C; const float* bias;
  long sA, sB, sC;
  int lda, ldb, ldc, K;
  int bias_mode; // 0 none, 1 per-col, 2 per-row
};

__global__ __launch_bounds__(256, 2) void gemm_big(GemmBigP p) {
  __shared__ __align__(16) bf16 As[128 * 32];
  __shared__ __align__(16) bf16 Bs[128 * 32];
  const int tid = threadIdx.x;
  const int wave = tid >> 6, lane = tid & 63;
  const int bn = blockIdx.x, bm = blockIdx.y, bz = blockIdx.z;
  const bf16* Ag = p.A + (long)bz * p.sA + (long)bm * 128 * p.lda;
  const bf16* Bg = p.B + (long)bz * p.sB + (long)bn * 128 * p.ldb;

  // staging: 512 16B chunks per matrix; thread stages chunks {tid, tid+256}.
  // chunk c -> LDS byte c*16 (row-major [128][32]); global row c>>2, k (c&3)*8.
  const char* ga0 = (const char*)(Ag + ((long)(tid >> 2) * p.lda + (tid & 3) * 8));
  const char* ga1 = (const char*)(Ag + ((long)((tid >> 2) + 64) * p.lda + (tid & 3) * 8));
  const char* gb0 = (const char*)(Bg + ((long)(tid >> 2) * p.ldb + (tid & 3) * 8));
  const char* gb1 = (const char*)(Bg + ((long)((tid >> 2) + 64) * p.ldb + (tid & 3) * 8));
  char* lA0 = (char*)As + tid * 16;
  char* lB0 = (char*)Bs + tid * 16;

  const int m_in = lane & 15, q = lane >> 4;
  const int wm = (wave & 1) * 64, wn = (wave >> 1) * 64;
  f32x4 acc[4][4] = {};

  u32x4 ra0 = *(const u32x4*)ga0;
  u32x4 ra1 = *(const u32x4*)ga1;
  u32x4 rb0 = *(const u32x4*)gb0;
  u32x4 rb1 = *(const u32x4*)gb1;

  for (int k0 = 0; k0 < p.K; k0 += 32) {
    __syncthreads();
    *(u32x4*)lA0 = ra0;
    *(u32x4*)(lA0 + 4096) = ra1;
    *(u32x4*)lB0 = rb0;
    *(u32x4*)(lB0 + 4096) = rb1;
    __syncthreads();
    if (k0 + 32 < p.K) {  // prefetch next tile while MFMAs run
      const long kb = (long)(k0 + 32) * 2;
      ra0 = *(const u32x4*)(ga0 + kb);
      ra1 = *(const u32x4*)(ga1 + kb);
      rb0 = *(const u32x4*)(gb0 + kb);
      rb1 = *(const u32x4*)(gb1 + kb);
    }
    bf16x8 af[4], bv[4];
#pragma unroll
    for (int i = 0; i < 4; i++)
      af[i] = *(const bf16x8*)(As + (wm + i * 16 + m_in) * 32 + q * 8);
#pragma unroll
    for (int j = 0; j < 4; j++)
      bv[j] = *(const bf16x8*)(Bs + (wn + j * 16 + m_in) * 32 + q * 8);
#pragma unroll
    for (int i = 0; i < 4; i++)
#pragma unroll
      for (int j = 0; j < 4; j++)
        acc[i][j] = __builtin_amdgcn_mfma_f32_16x16x32_bf16(af[i], bv[j], acc[i][j], 0, 0, 0);
  }

  bf16* Cg = p.C + (long)bz * p.sC;
  const long row0 = (long)bm * 128 + wm + q * 4;
  const long col0 = (long)bn * 128 + wn + m_in;
#pragma unroll
  for (int i = 0; i < 4; i++)
#pragma unroll
    for (int j = 0; j < 4; j++) {
      long r = row0 + i * 16;
      long c = col0 + j * 16;
      float badd = (p.bias_mode == 1) ? p.bias[c] : 0.f;
#pragma unroll
      for (int t = 0; t < 4; t++) {
        float v = acc[i][j][t] + badd;
        if (p.bias_mode == 2) v += p.bias[r + t];
        Cg[(r + t) * p.ldc + c] = f2bf(v);
      }
    }
}

// ---------------------------------------------------------------- small GEMM
// 64x64 tile, BK=32, 2-level batch (z = z1*nb2+z2). M%64==N%64==K%32==0.
struct GemmSmP {
  const bf16* A; const bf16* B; void* C; const float* bias; const float* res;
  long sA1, sA2, sB1, sB2, sC1, sC2, sBias2;
  int nb2, lda, ldb, ldc, K;
  int bias_mode;  // 0 none, 1 per-col
  int out_mode;   // 0 f32 (+res), 1 bf16, 2 gelu->bf16
  float scale;
};

__global__ __launch_bounds__(256, 2) void gemm_sm(GemmSmP p) {
  __shared__ __align__(16) bf16 As[64 * 32];
  __shared__ __align__(16) bf16 Bs[64 * 32];
  const int tid = threadIdx.x;
  const int wave = tid >> 6, lane = tid & 63;
  const int bn = blockIdx.x, bm = blockIdx.y, bz = blockIdx.z;
  const int z1 = bz / p.nb2, z2 = bz - z1 * p.nb2;
  const bf16* Ag = p.A + p.sA1 * z1 + p.sA2 * z2 + (long)bm * 64 * p.lda;
  const bf16* Bg = p.B + p.sB1 * z1 + p.sB2 * z2 + (long)bn * 64 * p.ldb;

  // 64x32 tile = 256 16B chunks per matrix; thread tid stages chunk tid of
  // BOTH A and B. chunk c -> LDS byte c*16; global row c>>2, k-off (c&3)*8.
  const char* gpa = (const char*)(Ag + ((long)(tid >> 2) * p.lda + (tid & 3) * 8));
  const char* gpb = (const char*)(Bg + ((long)(tid >> 2) * p.ldb + (tid & 3) * 8));
  char* lpa = (char*)As + tid * 16;
  char* lpb = (char*)Bs + tid * 16;

  const int m_in = lane & 15, q = lane >> 4;
  const int wm = (wave & 1) * 32, wn = (wave >> 1) * 32;
  f32x4 acc[2][2] = {};

  u32x4 rga = *(const u32x4*)gpa;
  u32x4 rgb = *(const u32x4*)gpb;
  for (int k0 = 0; k0 < p.K; k0 += 32) {
    __syncthreads();
    *(u32x4*)lpa = rga;
    *(u32x4*)lpb = rgb;
    __syncthreads();
    if (k0 + 32 < p.K) {
      const long kb = (long)(k0 + 32) * 2;
      rga = *(const u32x4*)(gpa + kb);
      rgb = *(const u32x4*)(gpb + kb);
    }
    bf16x8 a0 = *(const bf16x8*)(As + (wm + m_in) * 32 + q * 8);
    bf16x8 a1 = *(const bf16x8*)(As + (wm + 16 + m_in) * 32 + q * 8);
    bf16x8 b0 = *(const bf16x8*)(Bs + (wn + m_in) * 32 + q * 8);
    bf16x8 b1 = *(const bf16x8*)(Bs + (wn + 16 + m_in) * 32 + q * 8);
    acc[0][0] = __builtin_amdgcn_mfma_f32_16x16x32_bf16(a0, b0, acc[0][0], 0, 0, 0);
    acc[0][1] = __builtin_amdgcn_mfma_f32_16x16x32_bf16(a0, b1, acc[0][1], 0, 0, 0);
    acc[1][0] = __builtin_amdgcn_mfma_f32_16x16x32_bf16(a1, b0, acc[1][0], 0, 0, 0);
    acc[1][1] = __builtin_amdgcn_mfma_f32_16x16x32_bf16(a1, b1, acc[1][1], 0, 0, 0);
  }

  const long row0 = (long)bm * 64 + wm + q * 4;
  const long col0 = (long)bn * 64 + wn + m_in;
  const float* bias = p.bias + p.sBias2 * z2;
#pragma unroll
  for (int i = 0; i < 2; i++)
#pragma unroll
    for (int j = 0; j < 2; j++) {
      long r = row0 + i * 16;
      long cc = col0 + j * 16;
      float badd = (p.bias_mode == 1) ? bias[cc] : 0.f;
#pragma unroll
      for (int t = 0; t < 4; t++) {
        float v = acc[i][j][t] * p.scale + badd;
        long idx = (r + t) * p.ldc + cc;
        if (p.out_mode == 0) {
          float* Cf = (float*)p.C + p.sC1 * z1 + p.sC2 * z2;
          if (p.res) v += p.res[idx];
          Cf[idx] = v;
        } else {
          bf16* Cb = (bf16*)p.C + p.sC1 * z1 + p.sC2 * z2;
          if (p.out_mode == 2) v = gelu_f(v);
          Cb[idx] = f2bf(v);
        }
      }
    }
}

// ---------------------------------------------------------------- transpose (f32 in -> bf16 out)
// in [R][C] f32 -> out [C][R] bf16, 64x64 tiles, batched by z. R,C mult of 64.
struct TrP { const float* in; bf16* out; int R, C; long sIn, sOut; };

__global__ __launch_bounds__(256) void transpose_f2b(TrP p) {
  __shared__ __align__(16) bf16 tile[64][80];  // stride 160B: 16B-aligned rows
  const int tid = threadIdx.x;
  const int ct = blockIdx.x, rt = blockIdx.y, z = blockIdx.z;
  const float* in = p.in + p.sIn * z + ((long)rt * 64) * p.C + (long)ct * 64;
  bf16* out = p.out + p.sOut * z + ((long)ct * 64) * p.R + (long)rt * 64;
  const int r = tid >> 3, c8 = (tid & 7) * 8;
#pragma unroll
  for (int h = 0; h < 2; h++) {
    int rr = r + h * 32;
    float4 a = *(const float4*)(in + (long)rr * p.C + c8);
    float4 b = *(const float4*)(in + (long)rr * p.C + c8 + 4);
    u32 w[4];
    w[0] = f2bfu(a.x) | (f2bfu(a.y) << 16);
    w[1] = f2bfu(a.z) | (f2bfu(a.w) << 16);
    w[2] = f2bfu(b.x) | (f2bfu(b.y) << 16);
    w[3] = f2bfu(b.z) | (f2bfu(b.w) << 16);
    *(u32x4*)&tile[rr][c8] = *(u32x4*)w;
  }
  __syncthreads();
  const int co = tid >> 3, r8 = (tid & 7) * 8;
#pragma unroll
  for (int h = 0; h < 2; h++) {
    int cc = co + h * 32;
    __align__(16) bf16 tmp[8];
#pragma unroll
    for (int j = 0; j < 8; j++) tmp[j] = tile[r8 + j][cc];
    *(u32x4*)(out + (long)cc * p.R + r8) = *(const u32x4*)tmp;
  }
}

// ---------------------------------------------------------------- softmax (rows of 4096, in-place bf16)
__global__ __launch_bounds__(256) void softmax_rows(bf16* X) {
  const long row = blockIdx.x;
  u32* x = (u32*)(X + row * 4096);
  const int tid = threadIdx.x;
  const int lane = tid & 63, wave = tid >> 6;
  u32 d[8];
  *(u32x4*)&d[0] = ((const u32x4*)x)[tid * 2];
  *(u32x4*)&d[4] = ((const u32x4*)x)[tid * 2 + 1];
  float v[16];
#pragma unroll
  for (int j = 0; j < 8; j++) {
    v[2 * j] = __uint_as_float(d[j] << 16);
    v[2 * j + 1] = __uint_as_float(d[j] & 0xffff0000u);
  }
  float m = v[0];
#pragma unroll
  for (int i = 1; i < 16; i++) m = fmaxf(m, v[i]);
  for (int off = 32; off; off >>= 1) m = fmaxf(m, __shfl_xor(m, off));
  __shared__ float sm1[4], sm2[4];
  if (lane == 0) sm1[wave] = m;
  __syncthreads();
  m = fmaxf(fmaxf(sm1[0], sm1[1]), fmaxf(sm1[2], sm1[3]));
  float s = 0.f;
#pragma unroll
  for (int i = 0; i < 16; i++) { v[i] = __expf(v[i] - m); s += v[i]; }
  for (int off = 32; off; off >>= 1) s += __shfl_xor(s, off);
  if (lane == 0) sm2[wave] = s;
  __syncthreads();
  s = sm2[0] + sm2[1] + sm2[2] + sm2[3];
  const float inv = 1.f / s;
#pragma unroll
  for (int j = 0; j < 8; j++) {
    u32 lo = f2bfu(v[2 * j] * inv);
    u32 hi = f2bfu(v[2 * j + 1] * inv);
    d[j] = lo | (hi << 16);
  }
  ((u32x4*)x)[tid * 2] = *(u32x4*)&d[0];
  ((u32x4*)x)[tid * 2 + 1] = *(u32x4*)&d[4];
}

// ---------------------------------------------------------------- layernorm (rows of 768)
__global__ __launch_bounds__(256) void ln_rows(const float* in, const float* g, const float* b,
                                               float* outf, bf16* outb) {
  const long row = blockIdx.x;
  const float* x = in + row * 768;
  const int tid = threadIdx.x;
  const int lane = tid & 63, wave = tid >> 6;
  float v0 = x[tid], v1 = x[tid + 256], v2 = x[tid + 512];
  float s = v0 + v1 + v2;
  float s2 = v0 * v0 + v1 * v1 + v2 * v2;
  for (int off = 32; off; off >>= 1) { s += __shfl_xor(s, off); s2 += __shfl_xor(s2, off); }
  __shared__ float sa[4], sb[4];
  if (lane == 0) { sa[wave] = s; sb[wave] = s2; }
  __syncthreads();
  s = sa[0] + sa[1] + sa[2] + sa[3];
  s2 = sb[0] + sb[1] + sb[2] + sb[3];
  const float mean = s * (1.f / 768.f);
  const float var = s2 * (1.f / 768.f) - mean * mean;
  const float rs = rsqrtf(var + 1e-5f);
  float o0 = (v0 - mean) * rs * g[tid] + b[tid];
  float o1 = (v1 - mean) * rs * g[tid + 256] + b[tid + 256];
  float o2 = (v2 - mean) * rs * g[tid + 512] + b[tid + 512];
  if (outf) { float* of = outf + row * 768; of[tid] = o0; of[tid + 256] = o1; of[tid + 512] = o2; }
  if (outb) { bf16* ob = outb + row * 768; ob[tid] = f2bf(o0); ob[tid + 256] = f2bf(o1); ob[tid + 512] = f2bf(o2); }
}

// ---------------------------------------------------------------- misc elementwise
__global__ __launch_bounds__(256) void addqc(const float* x, const float* qc, float* qf, bf16* qb) {
  const long i = (long)blockIdx.x * 256 + threadIdx.x;  // 393216 total
  const int md = (int)(i % 49152);
  float v = x[i] + qc[md];
  qf[i] = v;
  qb[i] = f2bf(v);
}

__global__ __launch_bounds__(256) void reduce8(const float* in, float* outf, bf16* outb) {
  const long i = (long)blockIdx.x * 256 + threadIdx.x;  // n = 393216
  float s = 0.f;
#pragma unroll
  for (int cc = 0; cc < 8; cc++) s += in[(long)cc * 393216 + i];
  if (outb) outb[i] = f2bf(s);
  else outf[i] = s;
}

// ================================================================ launcher
extern "C" void kernel_launch(void* const* d_in, const int* in_sizes, int n_in,
                              void* d_out, int out_size, void* d_ws, size_t ws_size,
                              hipStream_t stream) {
  (void)in_sizes; (void)n_in; (void)out_size; (void)ws_size;
  const float* tokens   = (const float*)d_in[0];
  const float* selector = (const float*)d_in[1];
  const float* qc  = (const float*)d_in[2];
  const float* qw  = (const float*)d_in[3];
  const float* qb  = (const float*)d_in[4];
  const float* kw  = (const float*)d_in[5];
  const float* kb  = (const float*)d_in[6];
  const float* vw  = (const float*)d_in[7];
  const float* vb  = (const float*)d_in[8];
  const float* hw  = (const float*)d_in[9];
  const float* hb  = (const float*)d_in[10];
  const float* ow  = (const float*)d_in[11];
  const float* ob  = (const float*)d_in[12];
  const float* w1  = (const float*)d_in[13];
  const float* b1  = (const float*)d_in[14];
  const float* w2  = (const float*)d_in[15];
  const float* b2  = (const float*)d_in[16];
  const float* g1  = (const float*)d_in[17];
  const float* be1 = (const float*)d_in[18];
  const float* g2  = (const float*)d_in[19];
  const float* be2 = (const float*)d_in[20];
  float* out = (float*)d_out;

  char* ws = (char*)d_ws;
  size_t off = 0;
  auto alloc = [&](size_t bytes) { char* pp = ws + off; off += (bytes + 255) & ~(size_t)255; return pp; };
  // REGION0 (50.33 MB): tokens^T bf16 [B,D,N] during pooling; afterwards
  // reused as PBUF2 [4,H,M,N] + KBUF2 [4,N,768].
  bf16* TOKT  = (bf16*)alloc(50331648);
  bf16* PBUF2 = TOKT;                     // 12582912 elems
  bf16* KBUF2 = TOKT + 12582912;          // 12582912 elems
  bf16* TOKB  = (bf16*)alloc(50331648);   // tokens bf16 [B,N,D] (lives whole run)
  bf16* VTB2  = (bf16*)alloc(25165824);   // v^T [4,768,N]
  bf16* PLOG  = (bf16*)alloc(4194304);    // pooling logits [B,M,N]
  bf16* SELB  = (bf16*)alloc(98304);      // selector bf16 [M,D]
  // per-layer weight transposes (reused each layer)
  bf16* QWT   = (bf16*)alloc(1179648);
  bf16* KWT   = (bf16*)alloc(1179648);
  bf16* VWT   = (bf16*)alloc(1179648);
  bf16* HWT   = (bf16*)alloc(98304);
  bf16* OWT   = (bf16*)alloc(1179648);
  bf16* W1T   = (bf16*)alloc(4718592);
  bf16* W2T   = (bf16*)alloc(4718592);
  bf16* QBUF  = (bf16*)alloc(786432);     // q [B,M,H,HD]
  bf16* OBUF  = (bf16*)alloc(786432);     // attn out [B,H,M,HD]
  bf16* O2BUF = (bf16*)alloc(786432);     // head-mixed concat [B*M,768]
  float* XBUF = (float*)alloc(1572864);   // x f32
  float* QF   = (float*)alloc(1572864);   // queries f32
  bf16* QB16  = (bf16*)alloc(786432);
  float* T1   = (float*)alloc(1572864);
  float* X1F  = (float*)alloc(1572864);
  bf16* X1B   = (bf16*)alloc(786432);
  bf16* H1    = (bf16*)alloc(3145728);    // gelu(mlp1) [512,3072]
  float* T2   = (float*)alloc(1572864);
  float* OPART = (float*)alloc(12582912); // split-K partials [8][393216]

  auto tr = [&](const float* in, bf16* o, int R, int C, long s, int slabs) {
    TrP t{in, o, R, C, s, s};
    transpose_f2b<<<dim3(C / 64, R / 64, slabs), 256, 0, stream>>>(t);
  };
  // input conversions
  cvt_f2b<<<12288, 256, 0, stream>>>(tokens, TOKB, 25165824);
  cvt_f2b<<<24, 256, 0, stream>>>(selector, SELB, 49152);
  tr(tokens, TOKT, 4096, 768, 3145728, 8);

  // ---- pooling: logits = selector · tokens^T, softmax over n, x = P · tokens
  {
    GemmSmP p{}; p.A = SELB; p.B = TOKB; p.C = PLOG; p.bias = nullptr; p.res = nullptr;
    p.sB1 = 3145728; p.sC1 = 262144; p.nb2 = 1;
    p.lda = 768; p.ldb = 768; p.ldc = 4096; p.K = 768;
    p.bias_mode = 0; p.out_mode = 1; p.scale = 1.0f;
    gemm_sm<<<dim3(64, 1, 8), 256, 0, stream>>>(p);
  }
  softmax_rows<<<512, 256, 0, stream>>>(PLOG);
  {
    GemmSmP p{}; p.A = PLOG; p.B = TOKT; p.C = OPART; p.bias = nullptr; p.res = nullptr;
    p.sA1 = 512; p.sA2 = 262144; p.sB1 = 512; p.sB2 = 3145728;
    p.sC1 = 393216; p.sC2 = 49152; p.nb2 = 8;
    p.lda = 4096; p.ldb = 4096; p.ldc = 768; p.K = 512;
    p.bias_mode = 0; p.out_mode = 0; p.scale = 1.0f;
    gemm_sm<<<dim3(12, 1, 64), 256, 0, stream>>>(p);  // z = chunk*8 + b
  }
  reduce8<<<1536, 256, 0, stream>>>(OPART, XBUF, nullptr);

  for (int l = 0; l < 4; l++) {
    // per-layer weight transposes (f32 -> bf16) into reusable buffers
    tr(qw + (long)l * 589824, QWT, 768, 64, 49152, 12);
    tr(kw + (long)l * 589824, KWT, 768, 64, 49152, 12);
    tr(vw + (long)l * 589824, VWT, 768, 64, 49152, 12);
    tr(hw + (long)l * 49152, HWT, 64, 64, 4096, 12);
    tr(ow + (long)l * 589824, OWT, 768, 768, 589824, 1);
    tr(w1 + (long)l * 2359296, W1T, 768, 3072, 2359296, 1);
    tr(w2 + (long)l * 2359296, W2T, 3072, 768, 2359296, 1);

    addqc<<<1536, 256, 0, stream>>>(XBUF, qc + l * 49152, QF, QB16);
    { // q = queries · qw^T + qb  -> [B,M,H,HD] bf16
      GemmSmP p{}; p.A = QB16; p.B = QWT; p.C = QBUF; p.bias = qb + l * 768; p.res = nullptr;
      p.nb2 = 1; p.lda = 768; p.ldb = 768; p.ldc = 768; p.K = 768;
      p.bias_mode = 1; p.out_mode = 1; p.scale = 1.0f;
      gemm_sm<<<dim3(12, 8, 1), 256, 0, stream>>>(p);
    }
    for (int g = 0; g < 2; g++) {  // two batch-halves: b in [g*4, g*4+4)
      const bf16* tokg = TOKB + (long)g * 12582912;
      const bf16* tokgT = nullptr;  // (tokens^T half handled via strides below)
      { // k = tokens · kw^T + kb -> KBUF2 [4*N,768]  (16384x768x768)
        GemmBigP p{}; p.A = tokg; p.B = KWT; p.C = KBUF2; p.bias = kb + l * 768;
        p.sA = 0; p.sB = 0; p.sC = 0; p.lda = 768; p.ldb = 768; p.ldc = 768; p.K = 768; p.bias_mode = 1;
        gemm_big<<<dim3(6, 128, 1), 256, 0, stream>>>(p);
      }
      { // v^T = vw^T · tokens^T + vb(row) -> VTB2 [4,768,N]  (batched over b_local)
        // B operand = tokens (contiguous in d): C[e,n] = sum_d vw[d,e]*tok[n,d]
        GemmBigP p{}; p.A = VWT; p.B = tokg; p.C = VTB2; p.bias = vb + l * 768;
        p.sA = 0; p.sB = 3145728; p.sC = 3145728; p.lda = 768; p.ldb = 768; p.ldc = 4096; p.K = 768; p.bias_mode = 2;
        gemm_big<<<dim3(32, 6, 4), 256, 0, stream>>>(p);
      }
      (void)tokgT;
      { // S = (q·k^T)*scale -> PBUF2 bf16 [4,H,M,N]  (z = b_local*12+h)
        GemmSmP p{}; p.A = QBUF + (long)g * 196608; p.B = KBUF2; p.C = PBUF2; p.bias = nullptr; p.res = nullptr;
        p.sA1 = 49152; p.sA2 = 64; p.sB1 = 3145728; p.sB2 = 64; p.sC1 = 3145728; p.sC2 = 262144;
        p.nb2 = 12; p.lda = 768; p.ldb = 768; p.ldc = 4096; p.K = 64;
        p.bias_mode = 0; p.out_mode = 1; p.scale = 0.125f;
        gemm_sm<<<dim3(64, 1, 48), 256, 0, stream>>>(p);
      }
      softmax_rows<<<3072, 256, 0, stream>>>(PBUF2);
      { // o partials = P · v (split-K by 8)   z = chunk*48 + (b_local*12+h)
        GemmSmP p{}; p.A = PBUF2; p.B = VTB2; p.C = OPART + (long)g * 196608; p.bias = nullptr; p.res = nullptr;
        p.sA1 = 512; p.sA2 = 262144; p.sB1 = 512; p.sB2 = 262144; p.sC1 = 393216; p.sC2 = 4096;
        p.nb2 = 48; p.lda = 4096; p.ldb = 4096; p.ldc = 64; p.K = 512;
        p.bias_mode = 0; p.out_mode = 0; p.scale = 1.0f;
        gemm_sm<<<dim3(1, 1, 384), 256, 0, stream>>>(p);
      }
    }
    reduce8<<<1536, 256, 0, stream>>>(OPART, nullptr, OBUF);
    { // head-mix: o2[b,m,h*64+f] = o[b,h,m,:]·hw[h]^T + hb[h]   z = b*12+h
      GemmSmP p{}; p.A = OBUF; p.B = HWT; p.C = O2BUF; p.bias = hb + l * 768; p.res = nullptr;
      p.sA1 = 49152; p.sA2 = 4096; p.sB1 = 0; p.sB2 = 4096; p.sC1 = 49152; p.sC2 = 64; p.sBias2 = 64;
      p.nb2 = 12; p.lda = 64; p.ldb = 64; p.ldc = 768; p.K = 64;
      p.bias_mode = 1; p.out_mode = 1; p.scale = 1.0f;
      gemm_sm<<<dim3(1, 1, 96), 256, 0, stream>>>(p);
    }
    { // o3 = o2 · ow^T + ob + queries (f32)
      GemmSmP p{}; p.A = O2BUF; p.B = OWT; p.C = T1; p.bias = ob + l * 768; p.res = QF;
      p.nb2 = 1; p.lda = 768; p.ldb = 768; p.ldc = 768; p.K = 768;
      p.bias_mode = 1; p.out_mode = 0; p.scale = 1.0f;
      gemm_sm<<<dim3(12, 8, 1), 256, 0, stream>>>(p);
    }
    ln_rows<<<512, 256, 0, stream>>>(T1, g1 + l * 768, be1 + l * 768, X1F, X1B);
    { // mlp1 = gelu(x1 · w1^T + b1) bf16
      GemmSmP p{}; p.A = X1B; p.B = W1T; p.C = H1; p.bias = b1 + l * 3072; p.res = nullptr;
      p.nb2 = 1; p.lda = 768; p.ldb = 768; p.ldc = 3072; p.K = 768;
      p.bias_mode = 1; p.out_mode = 2; p.scale = 1.0f;
      gemm_sm<<<dim3(48, 8, 1), 256, 0, stream>>>(p);
    }
    { // mlp2 = h1 · w2^T + b2 + x1 (f32)
      GemmSmP p{}; p.A = H1; p.B = W2T; p.C = T2; p.bias = b2 + l * 768; p.res = X1F;
      p.nb2 = 1; p.lda = 3072; p.ldb = 3072; p.ldc = 768; p.K = 3072;
      p.bias_mode = 1; p.out_mode = 0; p.scale = 1.0f;
      gemm_sm<<<dim3(12, 8, 1), 256, 0, stream>>>(p);
    }
    ln_rows<<<512, 256, 0, stream>>>(T2, g2 + l * 768, be2 + l * 768, (l == 3) ? out : XBUF, nullptr);
  }
}

// Round 5
// 1572.281 us; speedup vs baseline: 1.0013x; 1.0013x over previous
//
#include <hip/hip_runtime.h>
#include <hip/hip_bf16.h>

// VisualDecoder: B=8,N=4096,D=768,H=12,M=64,L=4,HD=64. In/out f32; compute bf16
// MFMA (f32 accum). R4: async global_load_lds staging (m97 structure), full-batch
// attention, all-layer weight prep up-front, tokens cvt fused into transpose.

using bf16 = __hip_bfloat16;
typedef __attribute__((ext_vector_type(8))) __bf16 bf16x8;
typedef __attribute__((ext_vector_type(4))) float f32x4;
typedef unsigned int u32;
typedef __attribute__((ext_vector_type(4))) u32 u32x4;

#define DEVINL __device__ __forceinline__

DEVINL float bf2f(bf16 v) { return __bfloat162float(v); }
DEVINL bf16 f2bf(float v) { return __float2bfloat16(v); }
DEVINL u32 f2bfu(float f) { bf16 h = __float2bfloat16(f); return *(unsigned short*)&h; }
DEVINL float gelu_f(float x) { return 0.5f * x * (1.0f + erff(x * 0.70710678118654752f)); }

// async global->LDS, 16B per lane. LDS layout must be wave-base + lane*16 (ours is).
DEVINL void async16(const bf16* g, bf16* l) {
  __builtin_amdgcn_global_load_lds(
      (const __attribute__((address_space(1))) u32*)g,
      (__attribute__((address_space(3))) u32*)l, 16, 0, 0);
}

// ---------------------------------------------------------------- flat f32 -> bf16
__global__ __launch_bounds__(256) void cvt_f2b(const float* in, bf16* out, long n) {
  const long i = ((long)blockIdx.x * 256 + threadIdx.x) * 8;
  if (i >= n) return;
  float4 a = *(const float4*)(in + i);
  float4 b = *(const float4*)(in + i + 4);
  u32 w[4];
  w[0] = f2bfu(a.x) | (f2bfu(a.y) << 16);
  w[1] = f2bfu(a.z) | (f2bfu(a.w) << 16);
  w[2] = f2bfu(b.x) | (f2bfu(b.y) << 16);
  w[3] = f2bfu(b.z) | (f2bfu(b.w) << 16);
  *(u32x4*)(out + i) = *(u32x4*)w;
}

// ---------------------------------------------------------------- big GEMM
// 128x128 tile, BK=32, 256 thr = 4 waves (2x2 of 64x64), M%128==N%128==K%32==0.
struct GemmBigP {
  const bf16* A; const bf16* B; bf16* C; const float* bias;
  long sA, sB, sC;
  int lda, ldb, ldc, K;
  int bias_mode; // 0 none, 1 per-col, 2 per-row
};

__global__ __launch_bounds__(256, 2) void gemm_big(GemmBigP p) {
  __shared__ __align__(16) bf16 As[128 * 32];
  __shared__ __align__(16) bf16 Bs[128 * 32];
  const int tid = threadIdx.x;
  const int wave = tid >> 6, lane = tid & 63;
  const int bn = blockIdx.x, bm = blockIdx.y, bz = blockIdx.z;
  const bf16* Ag = p.A + (long)bz * p.sA + (long)bm * 128 * p.lda;
  const bf16* Bg = p.B + (long)bz * p.sB + (long)bn * 128 * p.ldb;

  // 512 16B chunks per matrix; thread stages chunks {tid, tid+256}.
  // chunk c -> LDS byte c*16 (row-major [128][32]); global row c>>2, k (c&3)*8.
  const bf16* ga0 = Ag + ((long)(tid >> 2) * p.lda + (tid & 3) * 8);
  const bf16* ga1 = Ag + ((long)((tid >> 2) + 64) * p.lda + (tid & 3) * 8);
  const bf16* gb0 = Bg + ((long)(tid >> 2) * p.ldb + (tid & 3) * 8);
  const bf16* gb1 = Bg + ((long)((tid >> 2) + 64) * p.ldb + (tid & 3) * 8);
  bf16* lA0 = As + tid * 8;
  bf16* lA1 = As + 2048 + tid * 8;
  bf16* lB0 = Bs + tid * 8;
  bf16* lB1 = Bs + 2048 + tid * 8;

  const int m_in = lane & 15, q = lane >> 4;
  const int wm = (wave & 1) * 64, wn = (wave >> 1) * 64;
  f32x4 acc[4][4] = {};

  for (int k0 = 0; k0 < p.K; k0 += 32) {
    async16(ga0 + k0, lA0);
    async16(ga1 + k0, lA1);
    async16(gb0 + k0, lB0);
    async16(gb1 + k0, lB1);
    __syncthreads();  // drains vmcnt(0): LDS tile visible
    bf16x8 af[4], bv[4];
#pragma unroll
    for (int i = 0; i < 4; i++)
      af[i] = *(const bf16x8*)(As + (wm + i * 16 + m_in) * 32 + q * 8);
#pragma unroll
    for (int j = 0; j < 4; j++)
      bv[j] = *(const bf16x8*)(Bs + (wn + j * 16 + m_in) * 32 + q * 8);
#pragma unroll
    for (int i = 0; i < 4; i++)
#pragma unroll
      for (int j = 0; j < 4; j++)
        acc[i][j] = __builtin_amdgcn_mfma_f32_16x16x32_bf16(af[i], bv[j], acc[i][j], 0, 0, 0);
    __syncthreads();  // protect LDS before next iteration's stores
  }

  bf16* Cg = p.C + (long)bz * p.sC;
  const long row0 = (long)bm * 128 + wm + q * 4;
  const long col0 = (long)bn * 128 + wn + m_in;
#pragma unroll
  for (int i = 0; i < 4; i++)
#pragma unroll
    for (int j = 0; j < 4; j++) {
      long r = row0 + i * 16;
      long c = col0 + j * 16;
      float badd = (p.bias_mode == 1) ? p.bias[c] : 0.f;
#pragma unroll
      for (int t = 0; t < 4; t++) {
        float v = acc[i][j][t] + badd;
        if (p.bias_mode == 2) v += p.bias[r + t];
        Cg[(r + t) * p.ldc + c] = f2bf(v);
      }
    }
}

// ---------------------------------------------------------------- small GEMM
// 64x64 tile, BK=32, 2-level batch (z = z1*nb2+z2). M%64==N%64==K%32==0.
struct GemmSmP {
  const bf16* A; const bf16* B; void* C; const float* bias; const float* res;
  long sA1, sA2, sB1, sB2, sC1, sC2, sBias2;
  int nb2, lda, ldb, ldc, K;
  int bias_mode;  // 0 none, 1 per-col
  int out_mode;   // 0 f32 (+res), 1 bf16, 2 gelu->bf16
  float scale;
};

__global__ __launch_bounds__(256, 2) void gemm_sm(GemmSmP p) {
  __shared__ __align__(16) bf16 As[64 * 32];
  __shared__ __align__(16) bf16 Bs[64 * 32];
  const int tid = threadIdx.x;
  const int wave = tid >> 6, lane = tid & 63;
  const int bn = blockIdx.x, bm = blockIdx.y, bz = blockIdx.z;
  const int z1 = bz / p.nb2, z2 = bz - z1 * p.nb2;
  const bf16* Ag = p.A + p.sA1 * z1 + p.sA2 * z2 + (long)bm * 64 * p.lda;
  const bf16* Bg = p.B + p.sB1 * z1 + p.sB2 * z2 + (long)bn * 64 * p.ldb;

  // 64x32 tile = 256 16B chunks per matrix; thread tid stages chunk tid of both.
  const bf16* gpa = Ag + ((long)(tid >> 2) * p.lda + (tid & 3) * 8);
  const bf16* gpb = Bg + ((long)(tid >> 2) * p.ldb + (tid & 3) * 8);
  bf16* lpa = As + tid * 8;
  bf16* lpb = Bs + tid * 8;

  const int m_in = lane & 15, q = lane >> 4;
  const int wm = (wave & 1) * 32, wn = (wave >> 1) * 32;
  f32x4 acc[2][2] = {};

  for (int k0 = 0; k0 < p.K; k0 += 32) {
    async16(gpa + k0, lpa);
    async16(gpb + k0, lpb);
    __syncthreads();
    bf16x8 a0 = *(const bf16x8*)(As + (wm + m_in) * 32 + q * 8);
    bf16x8 a1 = *(const bf16x8*)(As + (wm + 16 + m_in) * 32 + q * 8);
    bf16x8 b0 = *(const bf16x8*)(Bs + (wn + m_in) * 32 + q * 8);
    bf16x8 b1 = *(const bf16x8*)(Bs + (wn + 16 + m_in) * 32 + q * 8);
    acc[0][0] = __builtin_amdgcn_mfma_f32_16x16x32_bf16(a0, b0, acc[0][0], 0, 0, 0);
    acc[0][1] = __builtin_amdgcn_mfma_f32_16x16x32_bf16(a0, b1, acc[0][1], 0, 0, 0);
    acc[1][0] = __builtin_amdgcn_mfma_f32_16x16x32_bf16(a1, b0, acc[1][0], 0, 0, 0);
    acc[1][1] = __builtin_amdgcn_mfma_f32_16x16x32_bf16(a1, b1, acc[1][1], 0, 0, 0);
    __syncthreads();
  }

  const long row0 = (long)bm * 64 + wm + q * 4;
  const long col0 = (long)bn * 64 + wn + m_in;
  const float* bias = p.bias + p.sBias2 * z2;
#pragma unroll
  for (int i = 0; i < 2; i++)
#pragma unroll
    for (int j = 0; j < 2; j++) {
      long r = row0 + i * 16;
      long cc = col0 + j * 16;
      float badd = (p.bias_mode == 1) ? bias[cc] : 0.f;
#pragma unroll
      for (int t = 0; t < 4; t++) {
        float v = acc[i][j][t] * p.scale + badd;
        long idx = (r + t) * p.ldc + cc;
        if (p.out_mode == 0) {
          float* Cf = (float*)p.C + p.sC1 * z1 + p.sC2 * z2;
          if (p.res) v += p.res[idx];
          Cf[idx] = v;
        } else {
          bf16* Cb = (bf16*)p.C + p.sC1 * z1 + p.sC2 * z2;
          if (p.out_mode == 2) v = gelu_f(v);
          Cb[idx] = f2bf(v);
        }
      }
    }
}

// ---------------------------------------------------------------- transpose (f32 -> bf16)
// in [R][C] f32 -> out [C][R] bf16; optional outR = row-major bf16 copy.
struct TrP { const float* in; bf16* out; bf16* outR; int R, C; long sIn, sOut, sOutR; };

__global__ __launch_bounds__(256) void transpose_f2b(TrP p) {
  __shared__ __align__(16) bf16 tile[64][80];  // row stride 160B (16B-aligned)
  const int tid = threadIdx.x;
  const int ct = blockIdx.x, rt = blockIdx.y, z = blockIdx.z;
  const float* in = p.in + p.sIn * z + ((long)rt * 64) * p.C + (long)ct * 64;
  bf16* out = p.out + p.sOut * z + ((long)ct * 64) * p.R + (long)rt * 64;
  bf16* outR = p.outR ? p.outR + p.sOutR * z + ((long)rt * 64) * p.C + (long)ct * 64 : nullptr;
  const int r = tid >> 3, c8 = (tid & 7) * 8;
#pragma unroll
  for (int h = 0; h < 2; h++) {
    int rr = r + h * 32;
    float4 a = *(const float4*)(in + (long)rr * p.C + c8);
    float4 b = *(const float4*)(in + (long)rr * p.C + c8 + 4);
    u32 w[4];
    w[0] = f2bfu(a.x) | (f2bfu(a.y) << 16);
    w[1] = f2bfu(a.z) | (f2bfu(a.w) << 16);
    w[2] = f2bfu(b.x) | (f2bfu(b.y) << 16);
    w[3] = f2bfu(b.z) | (f2bfu(b.w) << 16);
    *(u32x4*)&tile[rr][c8] = *(u32x4*)w;
    if (outR) *(u32x4*)(outR + (long)rr * p.C + c8) = *(u32x4*)w;
  }
  __syncthreads();
  const int co = tid >> 3, r8 = (tid & 7) * 8;
#pragma unroll
  for (int h = 0; h < 2; h++) {
    int cc = co + h * 32;
    __align__(16) bf16 tmp[8];
#pragma unroll
    for (int j = 0; j < 8; j++) tmp[j] = tile[r8 + j][cc];
    *(u32x4*)(out + (long)cc * p.R + r8) = *(const u32x4*)tmp;
  }
}

// ---------------------------------------------------------------- softmax (rows of 4096, in-place bf16)
__global__ __launch_bounds__(256) void softmax_rows(bf16* X) {
  const long row = blockIdx.x;
  u32* x = (u32*)(X + row * 4096);
  const int tid = threadIdx.x;
  const int lane = tid & 63, wave = tid >> 6;
  u32 d[8];
  *(u32x4*)&d[0] = ((const u32x4*)x)[tid * 2];
  *(u32x4*)&d[4] = ((const u32x4*)x)[tid * 2 + 1];
  float v[16];
#pragma unroll
  for (int j = 0; j < 8; j++) {
    v[2 * j] = __uint_as_float(d[j] << 16);
    v[2 * j + 1] = __uint_as_float(d[j] & 0xffff0000u);
  }
  float m = v[0];
#pragma unroll
  for (int i = 1; i < 16; i++) m = fmaxf(m, v[i]);
  for (int off = 32; off; off >>= 1) m = fmaxf(m, __shfl_xor(m, off));
  __shared__ float sm1[4], sm2[4];
  if (lane == 0) sm1[wave] = m;
  __syncthreads();
  m = fmaxf(fmaxf(sm1[0], sm1[1]), fmaxf(sm1[2], sm1[3]));
  float s = 0.f;
#pragma unroll
  for (int i = 0; i < 16; i++) { v[i] = __expf(v[i] - m); s += v[i]; }
  for (int off = 32; off; off >>= 1) s += __shfl_xor(s, off);
  if (lane == 0) sm2[wave] = s;
  __syncthreads();
  s = sm2[0] + sm2[1] + sm2[2] + sm2[3];
  const float inv = 1.f / s;
#pragma unroll
  for (int j = 0; j < 8; j++) {
    u32 lo = f2bfu(v[2 * j] * inv);
    u32 hi = f2bfu(v[2 * j + 1] * inv);
    d[j] = lo | (hi << 16);
  }
  ((u32x4*)x)[tid * 2] = *(u32x4*)&d[0];
  ((u32x4*)x)[tid * 2 + 1] = *(u32x4*)&d[4];
}

// ---------------------------------------------------------------- layernorm (rows of 768)
__global__ __launch_bounds__(256) void ln_rows(const float* in, const float* g, const float* b,
                                               float* outf, bf16* outb) {
  const long row = blockIdx.x;
  const float* x = in + row * 768;
  const int tid = threadIdx.x;
  const int lane = tid & 63, wave = tid >> 6;
  float v0 = x[tid], v1 = x[tid + 256], v2 = x[tid + 512];
  float s = v0 + v1 + v2;
  float s2 = v0 * v0 + v1 * v1 + v2 * v2;
  for (int off = 32; off; off >>= 1) { s += __shfl_xor(s, off); s2 += __shfl_xor(s2, off); }
  __shared__ float sa[4], sb[4];
  if (lane == 0) { sa[wave] = s; sb[wave] = s2; }
  __syncthreads();
  s = sa[0] + sa[1] + sa[2] + sa[3];
  s2 = sb[0] + sb[1] + sb[2] + sb[3];
  const float mean = s * (1.f / 768.f);
  const float var = s2 * (1.f / 768.f) - mean * mean;
  const float rs = rsqrtf(var + 1e-5f);
  float o0 = (v0 - mean) * rs * g[tid] + b[tid];
  float o1 = (v1 - mean) * rs * g[tid + 256] + b[tid + 256];
  float o2 = (v2 - mean) * rs * g[tid + 512] + b[tid + 512];
  if (outf) { float* of = outf + row * 768; of[tid] = o0; of[tid + 256] = o1; of[tid + 512] = o2; }
  if (outb) { bf16* ob = outb + row * 768; ob[tid] = f2bf(o0); ob[tid + 256] = f2bf(o1); ob[tid + 512] = f2bf(o2); }
}

// ---------------------------------------------------------------- misc elementwise
__global__ __launch_bounds__(256) void addqc(const float* x, const float* qc, float* qf, bf16* qb) {
  const long i = (long)blockIdx.x * 256 + threadIdx.x;  // 393216 total
  const int md = (int)(i % 49152);
  float v = x[i] + qc[md];
  qf[i] = v;
  qb[i] = f2bf(v);
}

__global__ __launch_bounds__(256) void reduce8(const float* in, float* outf, bf16* outb) {
  const long i = (long)blockIdx.x * 256 + threadIdx.x;  // n = 393216
  float s = 0.f;
#pragma unroll
  for (int cc = 0; cc < 8; cc++) s += in[(long)cc * 393216 + i];
  if (outb) outb[i] = f2bf(s);
  else outf[i] = s;
}

// ================================================================ launcher
extern "C" void kernel_launch(void* const* d_in, const int* in_sizes, int n_in,
                              void* d_out, int out_size, void* d_ws, size_t ws_size,
                              hipStream_t stream) {
  (void)in_sizes; (void)n_in; (void)out_size; (void)ws_size;
  const float* tokens   = (const float*)d_in[0];
  const float* selector = (const float*)d_in[1];
  const float* qc  = (const float*)d_in[2];
  const float* qw  = (const float*)d_in[3];
  const float* qb  = (const float*)d_in[4];
  const float* kw  = (const float*)d_in[5];
  const float* kb  = (const float*)d_in[6];
  const float* vw  = (const float*)d_in[7];
  const float* vb  = (const float*)d_in[8];
  const float* hw  = (const float*)d_in[9];
  const float* hb  = (const float*)d_in[10];
  const float* ow  = (const float*)d_in[11];
  const float* ob  = (const float*)d_in[12];
  const float* w1  = (const float*)d_in[13];
  const float* b1  = (const float*)d_in[14];
  const float* w2  = (const float*)d_in[15];
  const float* b2  = (const float*)d_in[16];
  const float* g1  = (const float*)d_in[17];
  const float* be1 = (const float*)d_in[18];
  const float* g2  = (const float*)d_in[19];
  const float* be2 = (const float*)d_in[20];
  float* out = (float*)d_out;

  char* ws = (char*)d_ws;
  size_t off = 0;
  auto alloc = [&](size_t bytes) { char* pp = ws + off; off += (bytes + 255) & ~(size_t)255; return pp; };
  // REGION0: tokens^T bf16 [B,D,N] during pooling; then attention P [B,H,M,N].
  bf16* TOKT  = (bf16*)alloc(50331648);
  bf16* PBUF  = TOKT;
  bf16* TOKB  = (bf16*)alloc(50331648);   // tokens bf16 [B,N,D]
  bf16* KBUF  = (bf16*)alloc(50331648);   // k [B,N,H,HD]
  bf16* VTB   = (bf16*)alloc(50331648);   // v^T [B,768,N]
  bf16* PLOG  = (bf16*)alloc(4194304);    // pooling logits [B,M,N]
  bf16* SELB  = (bf16*)alloc(98304);      // selector bf16 [M,D]
  // all-layer weight transposes
  bf16* QWT   = (bf16*)alloc(4718592);    // [L,H,HD,D]
  bf16* KWT   = (bf16*)alloc(4718592);
  bf16* VWT   = (bf16*)alloc(4718592);
  bf16* HWT   = (bf16*)alloc(393216);     // [L,H,HD,HD]
  bf16* OWT   = (bf16*)alloc(4718592);    // [L,D,D]
  bf16* W1T   = (bf16*)alloc(18874368);   // [L,3072,768]
  bf16* W2T   = (bf16*)alloc(18874368);   // [L,768,3072]
  bf16* QBUF  = (bf16*)alloc(786432);     // q [B,M,H,HD]
  bf16* OBUF  = (bf16*)alloc(786432);     // attn out [B,H,M,HD]
  bf16* O2BUF = (bf16*)alloc(786432);     // head-mixed concat [B*M,768]
  float* XBUF = (float*)alloc(1572864);   // x f32
  float* QF   = (float*)alloc(1572864);   // queries f32
  bf16* QB16  = (bf16*)alloc(786432);
  float* T1   = (float*)alloc(1572864);
  float* X1F  = (float*)alloc(1572864);
  bf16* X1B   = (bf16*)alloc(786432);
  bf16* H1    = (bf16*)alloc(3145728);    // gelu(mlp1) [512,3072]
  float* T2   = (float*)alloc(1572864);
  float* OPART = (float*)alloc(12582912); // split-K partials [8][393216]

  auto tr = [&](const float* in, bf16* o, bf16* oR, int R, int C, long s, long sR, int slabs) {
    TrP t{in, o, oR, R, C, s, s, sR};
    transpose_f2b<<<dim3(C / 64, R / 64, slabs), 256, 0, stream>>>(t);
  };
  // input prep: tokens (transpose + fused row-major bf16 copy), selector, all weights
  tr(tokens, TOKT, TOKB, 4096, 768, 3145728, 3145728, 8);
  cvt_f2b<<<24, 256, 0, stream>>>(selector, SELB, 49152);
  tr(qw, QWT, nullptr, 768, 64, 49152, 0, 48);
  tr(kw, KWT, nullptr, 768, 64, 49152, 0, 48);
  tr(vw, VWT, nullptr, 768, 64, 49152, 0, 48);
  tr(hw, HWT, nullptr, 64, 64, 4096, 0, 48);
  tr(ow, OWT, nullptr, 768, 768, 589824, 0, 4);
  tr(w1, W1T, nullptr, 768, 3072, 2359296, 0, 4);
  tr(w2, W2T, nullptr, 3072, 768, 2359296, 0, 4);

  // ---- pooling: logits = selector · tokens^T, softmax over n, x = P · tokens
  {
    GemmSmP p{}; p.A = SELB; p.B = TOKB; p.C = PLOG; p.bias = nullptr; p.res = nullptr;
    p.sB1 = 3145728; p.sC1 = 262144; p.nb2 = 1;
    p.lda = 768; p.ldb = 768; p.ldc = 4096; p.K = 768;
    p.bias_mode = 0; p.out_mode = 1; p.scale = 1.0f;
    gemm_sm<<<dim3(64, 1, 8), 256, 0, stream>>>(p);
  }
  softmax_rows<<<512, 256, 0, stream>>>(PLOG);
  {
    GemmSmP p{}; p.A = PLOG; p.B = TOKT; p.C = OPART; p.bias = nullptr; p.res = nullptr;
    p.sA1 = 512; p.sA2 = 262144; p.sB1 = 512; p.sB2 = 3145728;
    p.sC1 = 393216; p.sC2 = 49152; p.nb2 = 8;
    p.lda = 4096; p.ldb = 4096; p.ldc = 768; p.K = 512;
    p.bias_mode = 0; p.out_mode = 0; p.scale = 1.0f;
    gemm_sm<<<dim3(12, 1, 64), 256, 0, stream>>>(p);  // z = chunk*8 + b
  }
  reduce8<<<1536, 256, 0, stream>>>(OPART, XBUF, nullptr);

  for (int l = 0; l < 4; l++) {
    addqc<<<1536, 256, 0, stream>>>(XBUF, qc + l * 49152, QF, QB16);
    { // q = queries · qw^T + qb  -> [B,M,H,HD] bf16
      GemmSmP p{}; p.A = QB16; p.B = QWT + l * 589824; p.C = QBUF; p.bias = qb + l * 768; p.res = nullptr;
      p.nb2 = 1; p.lda = 768; p.ldb = 768; p.ldc = 768; p.K = 768;
      p.bias_mode = 1; p.out_mode = 1; p.scale = 1.0f;
      gemm_sm<<<dim3(12, 8, 1), 256, 0, stream>>>(p);
    }
    { // k = tokens · kw^T + kb -> KBUF [B*N,768]  (32768x768x768)
      GemmBigP p{}; p.A = TOKB; p.B = KWT + l * 589824; p.C = KBUF; p.bias = kb + l * 768;
      p.sA = 0; p.sB = 0; p.sC = 0; p.lda = 768; p.ldb = 768; p.ldc = 768; p.K = 768; p.bias_mode = 1;
      gemm_big<<<dim3(6, 256, 1), 256, 0, stream>>>(p);
    }
    { // v^T = vw^T · tokens^T + vb(row) -> VTB [B,768,N]  (batched over b)
      GemmBigP p{}; p.A = VWT + l * 589824; p.B = TOKB; p.C = VTB; p.bias = vb + l * 768;
      p.sA = 0; p.sB = 3145728; p.sC = 3145728; p.lda = 768; p.ldb = 768; p.ldc = 4096; p.K = 768; p.bias_mode = 2;
      gemm_big<<<dim3(32, 6, 8), 256, 0, stream>>>(p);
    }
    { // S = (q·k^T)*scale -> PBUF bf16 [B,H,M,N]   (z = b*12+h)
      GemmSmP p{}; p.A = QBUF; p.B = KBUF; p.C = PBUF; p.bias = nullptr; p.res = nullptr;
      p.sA1 = 49152; p.sA2 = 64; p.sB1 = 3145728; p.sB2 = 64; p.sC1 = 3145728; p.sC2 = 262144;
      p.nb2 = 12; p.lda = 768; p.ldb = 768; p.ldc = 4096; p.K = 64;
      p.bias_mode = 0; p.out_mode = 1; p.scale = 0.125f;
      gemm_sm<<<dim3(64, 1, 96), 256, 0, stream>>>(p);
    }
    softmax_rows<<<6144, 256, 0, stream>>>(PBUF);
    { // o partials = P · v (split-K by 8)   z = chunk*96 + (b*12+h)
      GemmSmP p{}; p.A = PBUF; p.B = VTB; p.C = OPART; p.bias = nullptr; p.res = nullptr;
      p.sA1 = 512; p.sA2 = 262144; p.sB1 = 512; p.sB2 = 262144; p.sC1 = 393216; p.sC2 = 4096;
      p.nb2 = 96; p.lda = 4096; p.ldb = 4096; p.ldc = 64; p.K = 512;
      p.bias_mode = 0; p.out_mode = 0; p.scale = 1.0f;
      gemm_sm<<<dim3(1, 1, 768), 256, 0, stream>>>(p);
    }
    reduce8<<<1536, 256, 0, stream>>>(OPART, nullptr, OBUF);
    { // head-mix: o2[b,m,h*64+f] = o[b,h,m,:]·hw[h]^T + hb[h]   z = b*12+h
      GemmSmP p{}; p.A = OBUF; p.B = HWT + l * 49152; p.C = O2BUF; p.bias = hb + l * 768; p.res = nullptr;
      p.sA1 = 49152; p.sA2 = 4096; p.sB1 = 0; p.sB2 = 4096; p.sC1 = 49152; p.sC2 = 64; p.sBias2 = 64;
      p.nb2 = 12; p.lda = 64; p.ldb = 64; p.ldc = 768; p.K = 64;
      p.bias_mode = 1; p.out_mode = 1; p.scale = 1.0f;
      gemm_sm<<<dim3(1, 1, 96), 256, 0, stream>>>(p);
    }
    { // o3 = o2 · ow^T + ob + queries (f32)
      GemmSmP p{}; p.A = O2BUF; p.B = OWT + l * 589824; p.C = T1; p.bias = ob + l * 768; p.res = QF;
      p.nb2 = 1; p.lda = 768; p.ldb = 768; p.ldc = 768; p.K = 768;
      p.bias_mode = 1; p.out_mode = 0; p.scale = 1.0f;
      gemm_sm<<<dim3(12, 8, 1), 256, 0, stream>>>(p);
    }
    ln_rows<<<512, 256, 0, stream>>>(T1, g1 + l * 768, be1 + l * 768, X1F, X1B);
    { // mlp1 = gelu(x1 · w1^T + b1) bf16
      GemmSmP p{}; p.A = X1B; p.B = W1T + l * 2359296; p.C = H1; p.bias = b1 + l * 3072; p.res = nullptr;
      p.nb2 = 1; p.lda = 768; p.ldb = 768; p.ldc = 3072; p.K = 768;
      p.bias_mode = 1; p.out_mode = 2; p.scale = 1.0f;
      gemm_sm<<<dim3(48, 8, 1), 256, 0, stream>>>(p);
    }
    { // mlp2 = h1 · w2^T + b2 + x1 (f32)
      GemmSmP p{}; p.A = H1; p.B = W2T + l * 2359296; p.C = T2; p.bias = b2 + l * 768; p.res = X1F;
      p.nb2 = 1; p.lda = 3072; p.ldb = 3072; p.ldc = 768; p.K = 3072;
      p.bias_mode = 1; p.out_mode = 0; p.scale = 1.0f;
      gemm_sm<<<dim3(12, 8, 1), 256, 0, stream>>>(p);
    }
    ln_rows<<<512, 256, 0, stream>>>(T2, g2 + l * 768, be2 + l * 768, (l == 3) ? out : XBUF, nullptr);
  }
}

// Round 6
// 1422.660 us; speedup vs baseline: 1.1066x; 1.1052x over previous
//
#include <hip/hip_runtime.h>
#include <hip/hip_bf16.h>

// VisualDecoder: B=8,N=4096,D=768,H=12,M=64,L=4,HD=64. In/out f32; compute bf16
// MFMA (f32 accum). R6: double-buffered async global_load_lds pipeline (issue
// next tile AFTER barrier -> loads in flight during MFMA), split-K for o-proj
// and mlp2, addqc fused into ln/combine.

using bf16 = __hip_bfloat16;
typedef __attribute__((ext_vector_type(8))) __bf16 bf16x8;
typedef __attribute__((ext_vector_type(4))) float f32x4;
typedef unsigned int u32;
typedef __attribute__((ext_vector_type(4))) u32 u32x4;

#define DEVINL __device__ __forceinline__

DEVINL float bf2f(bf16 v) { return __bfloat162float(v); }
DEVINL bf16 f2bf(float v) { return __float2bfloat16(v); }
DEVINL u32 f2bfu(float f) { bf16 h = __float2bfloat16(f); return *(unsigned short*)&h; }
DEVINL float gelu_f(float x) { return 0.5f * x * (1.0f + erff(x * 0.70710678118654752f)); }

// async global->LDS, 16B per lane. LDS dest = wave-uniform base + lane*16 (ours is).
DEVINL void async16(const bf16* g, bf16* l) {
  __builtin_amdgcn_global_load_lds(
      (const __attribute__((address_space(1))) u32*)g,
      (__attribute__((address_space(3))) u32*)l, 16, 0, 0);
}

// ---------------------------------------------------------------- flat f32 -> bf16
__global__ __launch_bounds__(256) void cvt_f2b(const float* in, bf16* out, long n) {
  const long i = ((long)blockIdx.x * 256 + threadIdx.x) * 8;
  if (i >= n) return;
  float4 a = *(const float4*)(in + i);
  float4 b = *(const float4*)(in + i + 4);
  u32 w[4];
  w[0] = f2bfu(a.x) | (f2bfu(a.y) << 16);
  w[1] = f2bfu(a.z) | (f2bfu(a.w) << 16);
  w[2] = f2bfu(b.x) | (f2bfu(b.y) << 16);
  w[3] = f2bfu(b.z) | (f2bfu(b.w) << 16);
  *(u32x4*)(out + i) = *(u32x4*)w;
}

// ---------------------------------------------------------------- big GEMM
// 128x128 tile, BK=32, 256 thr = 4 waves (2x2 of 64x64). Double-buffered LDS:
// issue tile k+1 after the barrier, compute tile k -> loads overlap MFMA.
struct GemmBigP {
  const bf16* A; const bf16* B; bf16* C; const float* bias;
  long sA, sB, sC;
  int lda, ldb, ldc, K;
  int bias_mode; // 0 none, 1 per-col, 2 per-row
};

__global__ __launch_bounds__(256, 2) void gemm_big(GemmBigP p) {
  __shared__ __align__(16) bf16 As[2][128 * 32];
  __shared__ __align__(16) bf16 Bs[2][128 * 32];
  const int tid = threadIdx.x;
  const int wave = tid >> 6, lane = tid & 63;
  const int bn = blockIdx.x, bm = blockIdx.y, bz = blockIdx.z;
  const bf16* Ag = p.A + (long)bz * p.sA + (long)bm * 128 * p.lda;
  const bf16* Bg = p.B + (long)bz * p.sB + (long)bn * 128 * p.ldb;

  // 512 16B chunks per matrix; thread stages chunks {tid, tid+256}.
  // chunk c -> LDS byte c*16 (row-major [128][32]); global row c>>2, k (c&3)*8.
  const bf16* ga0 = Ag + ((long)(tid >> 2) * p.lda + (tid & 3) * 8);
  const bf16* ga1 = Ag + ((long)((tid >> 2) + 64) * p.lda + (tid & 3) * 8);
  const bf16* gb0 = Bg + ((long)(tid >> 2) * p.ldb + (tid & 3) * 8);
  const bf16* gb1 = Bg + ((long)((tid >> 2) + 64) * p.ldb + (tid & 3) * 8);

  const int m_in = lane & 15, q = lane >> 4;
  const int wm = (wave & 1) * 64, wn = (wave >> 1) * 64;
  f32x4 acc[4][4] = {};
  const int nk = p.K >> 5;

  // prologue: tile 0 -> buffer 0
  async16(ga0, &As[0][0] + tid * 8);
  async16(ga1, &As[0][0] + 2048 + tid * 8);
  async16(gb0, &Bs[0][0] + tid * 8);
  async16(gb1, &Bs[0][0] + 2048 + tid * 8);

  for (int k = 0; k < nk; ++k) {
    __syncthreads();  // auto vmcnt(0): buf[cur] loads (issued last iter) done
    const int cur = k & 1;
    if (k + 1 < nk) {  // issue next tile into other buffer; in flight during MFMA
      bf16* An = &As[cur ^ 1][0];
      bf16* Bn = &Bs[cur ^ 1][0];
      const int ko = (k + 1) * 32;
      async16(ga0 + ko, An + tid * 8);
      async16(ga1 + ko, An + 2048 + tid * 8);
      async16(gb0 + ko, Bn + tid * 8);
      async16(gb1 + ko, Bn + 2048 + tid * 8);
    }
    const bf16* Ac = &As[cur][0];
    const bf16* Bc = &Bs[cur][0];
    bf16x8 af[4], bv[4];
#pragma unroll
    for (int i = 0; i < 4; i++)
      af[i] = *(const bf16x8*)(Ac + (wm + i * 16 + m_in) * 32 + q * 8);
#pragma unroll
    for (int j = 0; j < 4; j++)
      bv[j] = *(const bf16x8*)(Bc + (wn + j * 16 + m_in) * 32 + q * 8);
#pragma unroll
    for (int i = 0; i < 4; i++)
#pragma unroll
      for (int j = 0; j < 4; j++)
        acc[i][j] = __builtin_amdgcn_mfma_f32_16x16x32_bf16(af[i], bv[j], acc[i][j], 0, 0, 0);
  }

  bf16* Cg = p.C + (long)bz * p.sC;
  const long row0 = (long)bm * 128 + wm + q * 4;
  const long col0 = (long)bn * 128 + wn + m_in;
#pragma unroll
  for (int i = 0; i < 4; i++)
#pragma unroll
    for (int j = 0; j < 4; j++) {
      long r = row0 + i * 16;
      long c = col0 + j * 16;
      float badd = (p.bias_mode == 1) ? p.bias[c] : 0.f;
#pragma unroll
      for (int t = 0; t < 4; t++) {
        float v = acc[i][j][t] + badd;
        if (p.bias_mode == 2) v += p.bias[r + t];
        Cg[(r + t) * p.ldc + c] = f2bf(v);
      }
    }
}

// ---------------------------------------------------------------- small GEMM
// 64x64 tile, BK=32, double-buffered async pipeline, 2-level batch.
struct GemmSmP {
  const bf16* A; const bf16* B; void* C; const float* bias; const float* res;
  long sA1, sA2, sB1, sB2, sC1, sC2, sBias2;
  int nb2, lda, ldb, ldc, K;
  int bias_mode;  // 0 none, 1 per-col
  int out_mode;   // 0 f32 (+res), 1 bf16, 2 gelu->bf16
  float scale;
};

__global__ __launch_bounds__(256, 2) void gemm_sm(GemmSmP p) {
  __shared__ __align__(16) bf16 As[2][64 * 32];
  __shared__ __align__(16) bf16 Bs[2][64 * 32];
  const int tid = threadIdx.x;
  const int wave = tid >> 6, lane = tid & 63;
  const int bn = blockIdx.x, bm = blockIdx.y, bz = blockIdx.z;
  const int z1 = bz / p.nb2, z2 = bz - z1 * p.nb2;
  const bf16* Ag = p.A + p.sA1 * z1 + p.sA2 * z2 + (long)bm * 64 * p.lda;
  const bf16* Bg = p.B + p.sB1 * z1 + p.sB2 * z2 + (long)bn * 64 * p.ldb;

  const bf16* gpa = Ag + ((long)(tid >> 2) * p.lda + (tid & 3) * 8);
  const bf16* gpb = Bg + ((long)(tid >> 2) * p.ldb + (tid & 3) * 8);

  const int m_in = lane & 15, q = lane >> 4;
  const int wm = (wave & 1) * 32, wn = (wave >> 1) * 32;
  f32x4 acc[2][2] = {};
  const int nk = p.K >> 5;

  async16(gpa, &As[0][0] + tid * 8);
  async16(gpb, &Bs[0][0] + tid * 8);

  for (int k = 0; k < nk; ++k) {
    __syncthreads();
    const int cur = k & 1;
    if (k + 1 < nk) {
      const int ko = (k + 1) * 32;
      async16(gpa + ko, &As[cur ^ 1][0] + tid * 8);
      async16(gpb + ko, &Bs[cur ^ 1][0] + tid * 8);
    }
    const bf16* Ac = &As[cur][0];
    const bf16* Bc = &Bs[cur][0];
    bf16x8 a0 = *(const bf16x8*)(Ac + (wm + m_in) * 32 + q * 8);
    bf16x8 a1 = *(const bf16x8*)(Ac + (wm + 16 + m_in) * 32 + q * 8);
    bf16x8 b0 = *(const bf16x8*)(Bc + (wn + m_in) * 32 + q * 8);
    bf16x8 b1 = *(const bf16x8*)(Bc + (wn + 16 + m_in) * 32 + q * 8);
    acc[0][0] = __builtin_amdgcn_mfma_f32_16x16x32_bf16(a0, b0, acc[0][0], 0, 0, 0);
    acc[0][1] = __builtin_amdgcn_mfma_f32_16x16x32_bf16(a0, b1, acc[0][1], 0, 0, 0);
    acc[1][0] = __builtin_amdgcn_mfma_f32_16x16x32_bf16(a1, b0, acc[1][0], 0, 0, 0);
    acc[1][1] = __builtin_amdgcn_mfma_f32_16x16x32_bf16(a1, b1, acc[1][1], 0, 0, 0);
  }

  const long row0 = (long)bm * 64 + wm + q * 4;
  const long col0 = (long)bn * 64 + wn + m_in;
  const float* bias = p.bias + p.sBias2 * z2;
#pragma unroll
  for (int i = 0; i < 2; i++)
#pragma unroll
    for (int j = 0; j < 2; j++) {
      long r = row0 + i * 16;
      long cc = col0 + j * 16;
      float badd = (p.bias_mode == 1) ? bias[cc] : 0.f;
#pragma unroll
      for (int t = 0; t < 4; t++) {
        float v = acc[i][j][t] * p.scale + badd;
        long idx = (r + t) * p.ldc + cc;
        if (p.out_mode == 0) {
          float* Cf = (float*)p.C + p.sC1 * z1 + p.sC2 * z2;
          if (p.res) v += p.res[idx];
          Cf[idx] = v;
        } else {
          bf16* Cb = (bf16*)p.C + p.sC1 * z1 + p.sC2 * z2;
          if (p.out_mode == 2) v = gelu_f(v);
          Cb[idx] = f2bf(v);
        }
      }
    }
}

// ---------------------------------------------------------------- transpose (f32 -> bf16)
struct TrP { const float* in; bf16* out; bf16* outR; int R, C; long sIn, sOut, sOutR; };

__global__ __launch_bounds__(256) void transpose_f2b(TrP p) {
  __shared__ __align__(16) bf16 tile[64][80];
  const int tid = threadIdx.x;
  const int ct = blockIdx.x, rt = blockIdx.y, z = blockIdx.z;
  const float* in = p.in + p.sIn * z + ((long)rt * 64) * p.C + (long)ct * 64;
  bf16* out = p.out + p.sOut * z + ((long)ct * 64) * p.R + (long)rt * 64;
  bf16* outR = p.outR ? p.outR + p.sOutR * z + ((long)rt * 64) * p.C + (long)ct * 64 : nullptr;
  const int r = tid >> 3, c8 = (tid & 7) * 8;
#pragma unroll
  for (int h = 0; h < 2; h++) {
    int rr = r + h * 32;
    float4 a = *(const float4*)(in + (long)rr * p.C + c8);
    float4 b = *(const float4*)(in + (long)rr * p.C + c8 + 4);
    u32 w[4];
    w[0] = f2bfu(a.x) | (f2bfu(a.y) << 16);
    w[1] = f2bfu(a.z) | (f2bfu(a.w) << 16);
    w[2] = f2bfu(b.x) | (f2bfu(b.y) << 16);
    w[3] = f2bfu(b.z) | (f2bfu(b.w) << 16);
    *(u32x4*)&tile[rr][c8] = *(u32x4*)w;
    if (outR) *(u32x4*)(outR + (long)rr * p.C + c8) = *(u32x4*)w;
  }
  __syncthreads();
  const int co = tid >> 3, r8 = (tid & 7) * 8;
#pragma unroll
  for (int h = 0; h < 2; h++) {
    int cc = co + h * 32;
    __align__(16) bf16 tmp[8];
#pragma unroll
    for (int j = 0; j < 8; j++) tmp[j] = tile[r8 + j][cc];
    *(u32x4*)(out + (long)cc * p.R + r8) = *(const u32x4*)tmp;
  }
}

// ---------------------------------------------------------------- softmax (rows of 4096, in-place bf16)
__global__ __launch_bounds__(256) void softmax_rows(bf16* X) {
  const long row = blockIdx.x;
  u32* x = (u32*)(X + row * 4096);
  const int tid = threadIdx.x;
  const int lane = tid & 63, wave = tid >> 6;
  u32 d[8];
  *(u32x4*)&d[0] = ((const u32x4*)x)[tid * 2];
  *(u32x4*)&d[4] = ((const u32x4*)x)[tid * 2 + 1];
  float v[16];
#pragma unroll
  for (int j = 0; j < 8; j++) {
    v[2 * j] = __uint_as_float(d[j] << 16);
    v[2 * j + 1] = __uint_as_float(d[j] & 0xffff0000u);
  }
  float m = v[0];
#pragma unroll
  for (int i = 1; i < 16; i++) m = fmaxf(m, v[i]);
  for (int off = 32; off; off >>= 1) m = fmaxf(m, __shfl_xor(m, off));
  __shared__ float sm1[4], sm2[4];
  if (lane == 0) sm1[wave] = m;
  __syncthreads();
  m = fmaxf(fmaxf(sm1[0], sm1[1]), fmaxf(sm1[2], sm1[3]));
  float s = 0.f;
#pragma unroll
  for (int i = 0; i < 16; i++) { v[i] = __expf(v[i] - m); s += v[i]; }
  for (int off = 32; off; off >>= 1) s += __shfl_xor(s, off);
  if (lane == 0) sm2[wave] = s;
  __syncthreads();
  s = sm2[0] + sm2[1] + sm2[2] + sm2[3];
  const float inv = 1.f / s;
#pragma unroll
  for (int j = 0; j < 8; j++) {
    u32 lo = f2bfu(v[2 * j] * inv);
    u32 hi = f2bfu(v[2 * j + 1] * inv);
    d[j] = lo | (hi << 16);
  }
  ((u32x4*)x)[tid * 2] = *(u32x4*)&d[0];
  ((u32x4*)x)[tid * 2 + 1] = *(u32x4*)&d[4];
}

// ---------------------------------------------------------------- layernorm (rows of 768)
// outputs: outf (f32), and/or outb (bf16), and/or queries = ln + qc (qf f32 + qb16).
__global__ __launch_bounds__(256) void ln_rows(const float* in, const float* g, const float* b,
                                               float* outf, bf16* outb,
                                               const float* qc, float* qf, bf16* qb16) {
  const long row = blockIdx.x;
  const float* x = in + row * 768;
  const int tid = threadIdx.x;
  const int lane = tid & 63, wave = tid >> 6;
  float v0 = x[tid], v1 = x[tid + 256], v2 = x[tid + 512];
  float s = v0 + v1 + v2;
  float s2 = v0 * v0 + v1 * v1 + v2 * v2;
  for (int off = 32; off; off >>= 1) { s += __shfl_xor(s, off); s2 += __shfl_xor(s2, off); }
  __shared__ float sa[4], sb[4];
  if (lane == 0) { sa[wave] = s; sb[wave] = s2; }
  __syncthreads();
  s = sa[0] + sa[1] + sa[2] + sa[3];
  s2 = sb[0] + sb[1] + sb[2] + sb[3];
  const float mean = s * (1.f / 768.f);
  const float var = s2 * (1.f / 768.f) - mean * mean;
  const float rs = rsqrtf(var + 1e-5f);
  float o0 = (v0 - mean) * rs * g[tid] + b[tid];
  float o1 = (v1 - mean) * rs * g[tid + 256] + b[tid + 256];
  float o2 = (v2 - mean) * rs * g[tid + 512] + b[tid + 512];
  if (outf) { float* of = outf + row * 768; of[tid] = o0; of[tid + 256] = o1; of[tid + 512] = o2; }
  if (outb) { bf16* ob = outb + row * 768; ob[tid] = f2bf(o0); ob[tid + 256] = f2bf(o1); ob[tid + 512] = f2bf(o2); }
  if (qc) {
    const float* qr = qc + (row & 63) * 768;
    float u0 = o0 + qr[tid], u1 = o1 + qr[tid + 256], u2 = o2 + qr[tid + 512];
    float* pf = qf + row * 768;
    pf[tid] = u0; pf[tid + 256] = u1; pf[tid + 512] = u2;
    bf16* pb = qb16 + row * 768;
    pb[tid] = f2bf(u0); pb[tid + 256] = f2bf(u1); pb[tid + 512] = f2bf(u2);
  }
}

// ---------------------------------------------------------------- combine split-K partials
// s = sum_{c<nch} in[c*393216+i] (+bias[i%768]) (+res[i]); outputs nullable.
struct CombP { const float* in; int nch; const float* bias; const float* res;
               float* outf; bf16* outb; const float* qc; float* qf; bf16* qb16; };

__global__ __launch_bounds__(256) void combine(CombP p) {
  const long i = (long)blockIdx.x * 256 + threadIdx.x;  // n = 393216
  float s = 0.f;
  for (int c = 0; c < p.nch; c++) s += p.in[(long)c * 393216 + i];
  if (p.bias) s += p.bias[i % 768];
  if (p.res) s += p.res[i];
  if (p.outf) p.outf[i] = s;
  if (p.outb) p.outb[i] = f2bf(s);
  if (p.qc) {
    float v = s + p.qc[i % 49152];
    p.qf[i] = v;
    p.qb16[i] = f2bf(v);
  }
}

// ================================================================ launcher
extern "C" void kernel_launch(void* const* d_in, const int* in_sizes, int n_in,
                              void* d_out, int out_size, void* d_ws, size_t ws_size,
                              hipStream_t stream) {
  (void)in_sizes; (void)n_in; (void)out_size; (void)ws_size;
  const float* tokens   = (const float*)d_in[0];
  const float* selector = (const float*)d_in[1];
  const float* qc  = (const float*)d_in[2];
  const float* qw  = (const float*)d_in[3];
  const float* qb  = (const float*)d_in[4];
  const float* kw  = (const float*)d_in[5];
  const float* kb  = (const float*)d_in[6];
  const float* vw  = (const float*)d_in[7];
  const float* vb  = (const float*)d_in[8];
  const float* hw  = (const float*)d_in[9];
  const float* hb  = (const float*)d_in[10];
  const float* ow  = (const float*)d_in[11];
  const float* ob  = (const float*)d_in[12];
  const float* w1  = (const float*)d_in[13];
  const float* b1  = (const float*)d_in[14];
  const float* w2  = (const float*)d_in[15];
  const float* b2  = (const float*)d_in[16];
  const float* g1  = (const float*)d_in[17];
  const float* be1 = (const float*)d_in[18];
  const float* g2  = (const float*)d_in[19];
  const float* be2 = (const float*)d_in[20];
  float* out = (float*)d_out;

  char* ws = (char*)d_ws;
  size_t off = 0;
  auto alloc = [&](size_t bytes) { char* pp = ws + off; off += (bytes + 255) & ~(size_t)255; return pp; };
  bf16* TOKT  = (bf16*)alloc(50331648);   // tokens^T [B,D,N]; later attention P
  bf16* PBUF  = TOKT;
  bf16* TOKB  = (bf16*)alloc(50331648);   // tokens bf16 [B,N,D]
  bf16* KBUF  = (bf16*)alloc(50331648);   // k [B,N,H,HD]
  bf16* VTB   = (bf16*)alloc(50331648);   // v^T [B,768,N]
  bf16* PLOG  = (bf16*)alloc(4194304);    // pooling logits [B,M,N]
  bf16* SELB  = (bf16*)alloc(98304);      // selector bf16 [M,D]
  bf16* QWT   = (bf16*)alloc(4718592);    // [L,H,HD,D]
  bf16* KWT   = (bf16*)alloc(4718592);
  bf16* VWT   = (bf16*)alloc(4718592);
  bf16* HWT   = (bf16*)alloc(393216);     // [L,H,HD,HD]
  bf16* OWT   = (bf16*)alloc(4718592);    // [L,D,D]
  bf16* W1T   = (bf16*)alloc(18874368);   // [L,3072,768]
  bf16* W2T   = (bf16*)alloc(18874368);   // [L,768,3072]
  bf16* QBUF  = (bf16*)alloc(786432);     // q [B,M,H,HD]
  bf16* OBUF  = (bf16*)alloc(786432);     // attn out [B,H,M,HD]
  bf16* O2BUF = (bf16*)alloc(786432);     // head-mixed concat [B*M,768]
  float* QF   = (float*)alloc(1572864);   // queries f32
  bf16* QB16  = (bf16*)alloc(786432);     // queries bf16
  float* T1   = (float*)alloc(1572864);
  float* X1F  = (float*)alloc(1572864);
  bf16* X1B   = (bf16*)alloc(786432);
  bf16* H1    = (bf16*)alloc(3145728);    // gelu(mlp1) [512,3072]
  float* T2   = (float*)alloc(1572864);
  float* OPART = (float*)alloc(12582912); // split-K partials [<=8][393216]

  auto tr = [&](const float* in, bf16* o, bf16* oR, int R, int C, long s, long sR, int slabs) {
    TrP t{in, o, oR, R, C, s, s, sR};
    transpose_f2b<<<dim3(C / 64, R / 64, slabs), 256, 0, stream>>>(t);
  };
  tr(tokens, TOKT, TOKB, 4096, 768, 3145728, 3145728, 8);
  cvt_f2b<<<24, 256, 0, stream>>>(selector, SELB, 49152);
  tr(qw, QWT, nullptr, 768, 64, 49152, 0, 48);
  tr(kw, KWT, nullptr, 768, 64, 49152, 0, 48);
  tr(vw, VWT, nullptr, 768, 64, 49152, 0, 48);
  tr(hw, HWT, nullptr, 64, 64, 4096, 0, 48);
  tr(ow, OWT, nullptr, 768, 768, 589824, 0, 4);
  tr(w1, W1T, nullptr, 768, 3072, 2359296, 0, 4);
  tr(w2, W2T, nullptr, 3072, 768, 2359296, 0, 4);

  // ---- pooling
  {
    GemmSmP p{}; p.A = SELB; p.B = TOKB; p.C = PLOG;
    p.sB1 = 3145728; p.sC1 = 262144; p.nb2 = 1;
    p.lda = 768; p.ldb = 768; p.ldc = 4096; p.K = 768;
    p.bias_mode = 0; p.out_mode = 1; p.scale = 1.0f;
    gemm_sm<<<dim3(64, 1, 8), 256, 0, stream>>>(p);
  }
  softmax_rows<<<512, 256, 0, stream>>>(PLOG);
  { // x partials = P · tokens (split-K 8 over N)
    GemmSmP p{}; p.A = PLOG; p.B = TOKT; p.C = OPART;
    p.sA1 = 512; p.sA2 = 262144; p.sB1 = 512; p.sB2 = 3145728;
    p.sC1 = 393216; p.sC2 = 49152; p.nb2 = 8;
    p.lda = 4096; p.ldb = 4096; p.ldc = 768; p.K = 512;
    p.bias_mode = 0; p.out_mode = 0; p.scale = 1.0f;
    gemm_sm<<<dim3(12, 1, 64), 256, 0, stream>>>(p);
  }
  { // x -> queries(l=0) = x + qc[0]
    CombP c{}; c.in = OPART; c.nch = 8; c.qc = qc; c.qf = QF; c.qb16 = QB16;
    combine<<<1536, 256, 0, stream>>>(c);
  }

  for (int l = 0; l < 4; l++) {
    { // q = queries · qw^T + qb  -> [B,M,H,HD] bf16
      GemmSmP p{}; p.A = QB16; p.B = QWT + l * 589824; p.C = QBUF; p.bias = qb + l * 768;
      p.nb2 = 1; p.lda = 768; p.ldb = 768; p.ldc = 768; p.K = 768;
      p.bias_mode = 1; p.out_mode = 1; p.scale = 1.0f;
      gemm_sm<<<dim3(12, 8, 1), 256, 0, stream>>>(p);
    }
    { // k = tokens · kw^T + kb -> KBUF [B*N,768]
      GemmBigP p{}; p.A = TOKB; p.B = KWT + l * 589824; p.C = KBUF; p.bias = kb + l * 768;
      p.sA = 0; p.sB = 0; p.sC = 0; p.lda = 768; p.ldb = 768; p.ldc = 768; p.K = 768; p.bias_mode = 1;
      gemm_big<<<dim3(6, 256, 1), 256, 0, stream>>>(p);
    }
    { // v^T = vw^T · tokens^T + vb(row) -> VTB [B,768,N]
      GemmBigP p{}; p.A = VWT + l * 589824; p.B = TOKB; p.C = VTB; p.bias = vb + l * 768;
      p.sA = 0; p.sB = 3145728; p.sC = 3145728; p.lda = 768; p.ldb = 768; p.ldc = 4096; p.K = 768; p.bias_mode = 2;
      gemm_big<<<dim3(32, 6, 8), 256, 0, stream>>>(p);
    }
    { // S = (q·k^T)*scale -> PBUF bf16 [B,H,M,N]   (z = b*12+h)
      GemmSmP p{}; p.A = QBUF; p.B = KBUF; p.C = PBUF;
      p.sA1 = 49152; p.sA2 = 64; p.sB1 = 3145728; p.sB2 = 64; p.sC1 = 3145728; p.sC2 = 262144;
      p.nb2 = 12; p.lda = 768; p.ldb = 768; p.ldc = 4096; p.K = 64;
      p.bias_mode = 0; p.out_mode = 1; p.scale = 0.125f;
      gemm_sm<<<dim3(64, 1, 96), 256, 0, stream>>>(p);
    }
    softmax_rows<<<6144, 256, 0, stream>>>(PBUF);
    { // o partials = P · v (split-K 8)   z = chunk*96 + (b*12+h)
      GemmSmP p{}; p.A = PBUF; p.B = VTB; p.C = OPART;
      p.sA1 = 512; p.sA2 = 262144; p.sB1 = 512; p.sB2 = 262144; p.sC1 = 393216; p.sC2 = 4096;
      p.nb2 = 96; p.lda = 4096; p.ldb = 4096; p.ldc = 64; p.K = 512;
      p.bias_mode = 0; p.out_mode = 0; p.scale = 1.0f;
      gemm_sm<<<dim3(1, 1, 768), 256, 0, stream>>>(p);
    }
    { CombP c{}; c.in = OPART; c.nch = 8; c.outb = OBUF; combine<<<1536, 256, 0, stream>>>(c); }
    { // head-mix   z = b*12+h
      GemmSmP p{}; p.A = OBUF; p.B = HWT + l * 49152; p.C = O2BUF; p.bias = hb + l * 768;
      p.sA1 = 49152; p.sA2 = 4096; p.sB1 = 0; p.sB2 = 4096; p.sC1 = 49152; p.sC2 = 64; p.sBias2 = 64;
      p.nb2 = 12; p.lda = 64; p.ldb = 64; p.ldc = 768; p.K = 64;
      p.bias_mode = 1; p.out_mode = 1; p.scale = 1.0f;
      gemm_sm<<<dim3(1, 1, 96), 256, 0, stream>>>(p);
    }
    { // o-proj partials (split-K 4): o2 · ow^T
      GemmSmP p{}; p.A = O2BUF; p.B = OWT + l * 589824; p.C = OPART;
      p.sA1 = 192; p.sB1 = 192; p.sC1 = 393216; p.nb2 = 1;
      p.lda = 768; p.ldb = 768; p.ldc = 768; p.K = 192;
      p.bias_mode = 0; p.out_mode = 0; p.scale = 1.0f;
      gemm_sm<<<dim3(12, 8, 4), 256, 0, stream>>>(p);
    }
    { CombP c{}; c.in = OPART; c.nch = 4; c.bias = ob + l * 768; c.res = QF; c.outf = T1;
      combine<<<1536, 256, 0, stream>>>(c); }
    ln_rows<<<512, 256, 0, stream>>>(T1, g1 + l * 768, be1 + l * 768, X1F, X1B, nullptr, nullptr, nullptr);
    { // mlp1 = gelu(x1 · w1^T + b1) bf16
      GemmSmP p{}; p.A = X1B; p.B = W1T + l * 2359296; p.C = H1; p.bias = b1 + l * 3072;
      p.nb2 = 1; p.lda = 768; p.ldb = 768; p.ldc = 3072; p.K = 768;
      p.bias_mode = 1; p.out_mode = 2; p.scale = 1.0f;
      gemm_sm<<<dim3(48, 8, 1), 256, 0, stream>>>(p);
    }
    { // mlp2 partials (split-K 8): h1 · w2^T
      GemmSmP p{}; p.A = H1; p.B = W2T + l * 2359296; p.C = OPART;
      p.sA1 = 384; p.sB1 = 384; p.sC1 = 393216; p.nb2 = 1;
      p.lda = 3072; p.ldb = 3072; p.ldc = 768; p.K = 384;
      p.bias_mode = 0; p.out_mode = 0; p.scale = 1.0f;
      gemm_sm<<<dim3(12, 8, 8), 256, 0, stream>>>(p);
    }
    { CombP c{}; c.in = OPART; c.nch = 8; c.bias = b2 + l * 768; c.res = X1F; c.outf = T2;
      combine<<<1536, 256, 0, stream>>>(c); }
    // second LN: for l<3 emit queries(l+1) = ln + qc[l+1]; for l==3 emit final out (f32)
    ln_rows<<<512, 256, 0, stream>>>(T2, g2 + l * 768, be2 + l * 768,
                                     (l == 3) ? out : nullptr, nullptr,
                                     (l < 3) ? (qc + (l + 1) * 49152) : nullptr, QF, QB16);
  }
}